// Round 8
// baseline (511.070 us; speedup 1.0000x reference)
//
#include <hip/hip_runtime.h>
#include <math.h>

#define N_NODES 32768
#define N_EDGES 524288
#define NODE_DIM 128
#define HIDDEN 256
#define EDGE_DIM 32
#define TE 64              // edges per block
#define ASTR 296           // smA row stride (bf16): 592 B, 16B-aligned
#define HSTR 264           // smH row stride (bf16): 528 B, 16B-aligned
#define MSTR 132           // smM row stride (f32): 528 B, 16B-aligned

typedef __attribute__((ext_vector_type(8))) short bf16x8;
typedef __attribute__((ext_vector_type(16))) float f32x16;

__device__ __forceinline__ float silu_f(float v) {
    float e = __expf(-v);
    return v * __builtin_amdgcn_rcpf(1.0f + e);
}

__device__ __forceinline__ unsigned short f2bf_rne(float f) {
    union { float f; unsigned int u; } v; v.f = f;
    return (unsigned short)((v.u + 0x7fffu + ((v.u >> 16) & 1u)) >> 16);
}
__device__ __forceinline__ unsigned int pk_rne(float a, float b) {
    return (unsigned int)f2bf_rne(a) | ((unsigned int)f2bf_rne(b) << 16);
}
// half-up pack of two floats -> (bf16(a) | bf16(b)<<16)
__device__ __forceinline__ unsigned int pkbf(float a, float b) {
    union { float f; unsigned int u; } ua, ub; ua.f = a; ub.f = b;
    return __builtin_amdgcn_perm(ub.u + 0x8000u, ua.u + 0x8000u, 0x07060302u);
}
__device__ __forceinline__ unsigned short f2bf_hu(float f) {
    union { float f; unsigned int u; } v; v.f = f;
    return (unsigned short)((v.u + 0x8000u) >> 16);
}

// uniform idx-width check: lanes sample the first 64 high words of ei.
// int64 node ids < 2^15 => all high words zero; int32 => random node ids.
__device__ __forceinline__ int detect_is64(const void* ei, int t) {
    const unsigned int* ew = (const unsigned int*)ei;
    unsigned int hiw = ew[2 * (t & 63) + 1];
    return (__ballot(hiw != 0u) == 0ULL) ? 1 : 0;
}

// ws layout (bytes):
//   1024    : biasC f32[512]
//   69632   : W1s bf16 swizzled (16 n-tiles x 18 steps x 64 lanes x 8)
//   364544  : W2s bf16 swizzled (4 d-tiles x 16 steps x 64 lanes x 8)
//   430080  : counts  int[32768]
//   561152  : cursor  int[32768]
//   692224  : perm    int[524288]
//   2789376 : hbf bf16[32768*128]  (optional, if ws_size permits)
#define WS_BIAS_OFF 1024
#define WS_W1S_OFF  69632
#define WS_W2S_OFF  364544
#define WS_CNT_OFF  430080
#define WS_CUR_OFF  561152
#define WS_PERM_OFF 692224
#define WS_HBF_OFF  2789376
#define WS_HBF_END  (WS_HBF_OFF + N_NODES * NODE_DIM * 2)

// one fused prep kernel; all segment boundaries are 256-aligned (no divergence)
#define SEG_CNT  32768
#define SEG_W1S  147456
#define SEG_W2S  32768
#define SEG_BIAS 512
#define SEG_OUT  1073152    // (N*128 + N*3)/4 float4
#define SEG_HBF  524288     // N*128/8 uint4 packs
#define PREP_TOT (SEG_CNT + SEG_W1S + SEG_W2S + SEG_BIAS + SEG_OUT + SEG_HBF)

__global__ void prep_all_kernel(const float* __restrict__ h, const float* __restrict__ x,
                                const float* __restrict__ We2, const float* __restrict__ be2,
                                const float* __restrict__ Wn1, const float* __restrict__ bn1,
                                const float* __restrict__ Wn2,
                                const float* __restrict__ Wc1, const float* __restrict__ bc1,
                                float* __restrict__ out, float* __restrict__ biasC,
                                unsigned short* __restrict__ W1s, unsigned short* __restrict__ W2s,
                                int* __restrict__ counts, unsigned short* __restrict__ hbf) {
    int i = blockIdx.x * 256 + threadIdx.x;
    if (i < SEG_CNT) { counts[i] = 0; return; }
    i -= SEG_CNT;
    if (i < SEG_W1S) {
        // B-frag order: idx = ((tile*18+step)*64+lane)*8+jj ; n = tile*32+(lane&31);
        // k = step*16+(lane>>5)*8+jj ; edge-MLP layer 2 folded for k >= 256
        int jj = i & 7, ln = (i >> 3) & 63, rest = i >> 9;
        int step = rest % 18, tile = rest / 18;
        int n = tile * 32 + (ln & 31);
        int k = step * 16 + ((ln >> 5) * 8) + jj;
        float v;
        if (k < 256) {
            v = (n < 256) ? Wn1[k * 256 + n] : Wc1[k * 256 + (n - 256)];
        } else {
            int j = k - 256;
            float s = 0.0f;
            #pragma unroll 8
            for (int q = 0; q < 32; ++q)
                s += We2[j * 32 + q] * ((n < 256) ? Wn1[(256 + q) * 256 + n]
                                                  : Wc1[(256 + q) * 256 + (n - 256)]);
            v = s;
        }
        W1s[i] = f2bf_rne(v);
        return;
    }
    i -= SEG_W1S;
    if (i < SEG_W2S) {
        int jj = i & 7, ln = (i >> 3) & 63, rest = i >> 9;
        int step = rest & 15, tile = rest >> 4;
        int d = tile * 32 + (ln & 31);
        int k = step * 16 + ((ln >> 5) * 8) + jj;
        W2s[i] = f2bf_rne(Wn2[k * 128 + d]);
        return;
    }
    i -= SEG_W2S;
    if (i < SEG_BIAS) {
        int n = i;
        float s = (n < 256) ? bn1[n] : bc1[n - 256];
        #pragma unroll 8
        for (int q = 0; q < 32; ++q)
            s += be2[q] * ((n < 256) ? Wn1[(256 + q) * 256 + n]
                                     : Wc1[(256 + q) * 256 + (n - 256)]);
        biasC[n] = s;
        return;
    }
    i -= SEG_BIAS;
    if (i < SEG_OUT) {
        const int NH4 = N_NODES * NODE_DIM / 4;
        const float4* h4 = (const float4*)h;
        const float4* x4 = (const float4*)x;
        ((float4*)out)[i] = (i < NH4) ? h4[i] : x4[i - NH4];
        return;
    }
    i -= SEG_OUT;
    if (hbf != nullptr && i < SEG_HBF) {
        const float4* p = (const float4*)&h[i * 8];
        float4 v0 = p[0], v1 = p[1];
        uint4 o = make_uint4(pk_rne(v0.x, v0.y), pk_rne(v0.z, v0.w),
                             pk_rne(v1.x, v1.y), pk_rne(v1.z, v1.w));
        *(uint4*)&hbf[i * 8] = o;
    }
}

__global__ void hist_kernel(const void* __restrict__ ei, int* __restrict__ counts) {
    int is64 = detect_is64(ei, threadIdx.x);
    int e = blockIdx.x * 256 + threadIdx.x;
    int dst = is64 ? (int)((const long long*)ei)[N_EDGES + e]
                   : ((const int*)ei)[N_EDGES + e];
    atomicAdd(&counts[dst], 1);
}

// single-block exclusive scan of 32768 counts -> cursor
__global__ __launch_bounds__(1024)
void scan_kernel(const int* __restrict__ counts, int* __restrict__ cursor) {
    __shared__ int part[1024];
    const int t = threadIdx.x;
    const int base = t * 32;
    int loc[32];
    int s = 0;
    #pragma unroll
    for (int i = 0; i < 32; ++i) { loc[i] = s; s += counts[base + i]; }
    part[t] = s;
    __syncthreads();
    #pragma unroll
    for (int d = 1; d < 1024; d <<= 1) {
        int v = (t >= d) ? part[t - d] : 0;
        __syncthreads();
        part[t] += v;
        __syncthreads();
    }
    int excl = part[t] - s;
    #pragma unroll
    for (int i = 0; i < 32; ++i) cursor[base + i] = excl + loc[i];
}

__global__ void place_kernel(const void* __restrict__ ei,
                             int* __restrict__ cursor, int* __restrict__ perm) {
    int is64 = detect_is64(ei, threadIdx.x);
    int e = blockIdx.x * 256 + threadIdx.x;
    int dst = is64 ? (int)((const long long*)ei)[N_EDGES + e]
                   : ((const int*)ei)[N_EDGES + e];
    int pos = atomicAdd(&cursor[dst], 1);
    perm[pos] = e;
}

__global__ __launch_bounds__(512, 4)
void egnn_mfma_kernel(const float* __restrict__ h, const float* __restrict__ x,
                      const void* __restrict__ ei, const float* __restrict__ dist,
                      const float* __restrict__ We1, const float* __restrict__ be1,
                      const float* __restrict__ bn2, const float* __restrict__ Wc2,
                      const float* __restrict__ biasC,
                      const unsigned short* __restrict__ W1s,
                      const unsigned short* __restrict__ W2s,
                      const int* __restrict__ perm,
                      const unsigned short* __restrict__ hbf,
                      float* __restrict__ out)
{
    // one overlapped region: smA (GEMM1 A) -> smH (GEMM2 A) -> smM (f32 m tile)
    __shared__ unsigned short smA[TE * ASTR];          // 37888 B
    __shared__ int sidx[TE], didx[TE], eidx[TE];
    __shared__ float cw_s[TE];
    __shared__ float cxyz[3 * TE];

    unsigned short* smH = smA;
    float* smM = (float*)smA;

    const int t = threadIdx.x;
    const int lane = t & 63;
    const int wv = t >> 6;       // 0..7
    const int lo = lane & 31;
    const int hi = lane >> 5;
    const int ebase = blockIdx.x * TE;
    const int is64 = detect_is64(ei, t);

    // ---- 1. permuted edge indices + zero cw ----
    if (t < 2 * TE) {
        int e = t & (TE - 1);
        int eid = perm[ebase + e];
        int which = t >> 6;              // 0 = src, 1 = dst
        long long pos = (long long)which * N_EDGES + eid;
        int idx = is64 ? (int)((const long long*)ei)[pos] : ((const int*)ei)[pos];
        if (which == 0) { sidx[e] = idx; eidx[e] = eid; }
        else didx[e] = idx;
        if (t < TE) cw_s[t] = 0.0f;
    }
    __syncthreads();

    // ---- 2a. gather h[src], h[dst] -> bf16 smA ----
    if (hbf != nullptr) {
        #pragma unroll
        for (int it = 0; it < 4; ++it) {
            int id = it * 512 + t;
            int g = id & 15;             // 16B unit within 128-dim half
            int half = (id >> 4) & 1;
            int e = id >> 5;
            int node = half ? didx[e] : sidx[e];
            uint4 v = *(const uint4*)&hbf[node * NODE_DIM + 8 * g];
            *(uint4*)&smA[e * ASTR + half * NODE_DIM + 8 * g] = v;
        }
    } else {
        #pragma unroll
        for (int it = 0; it < 4; ++it) {
            int id = it * 512 + t;
            int g8 = id & 15;
            int half = (id >> 4) & 1;
            int e = id >> 5;
            int node = half ? didx[e] : sidx[e];
            const float4* p = (const float4*)&h[node * NODE_DIM + 8 * g8];
            float4 v0 = p[0], v1 = p[1];
            unsigned int a0 = pkbf(v0.x, v0.y), a1 = pkbf(v0.z, v0.w);
            unsigned int a2 = pkbf(v1.x, v1.y), a3 = pkbf(v1.z, v1.w);
            *(uint4*)&smA[e * ASTR + half * NODE_DIM + 8 * g8] = make_uint4(a0, a1, a2, a3);
        }
    }
    // ---- 2b. t1 = silu(d*We1+be1) -> smA[:,256:288] (layer2 folded in W1s) ----
    {
        int e = t >> 3;
        int j4 = (t & 7) * 4;
        float d = dist[eidx[e]];
        float s0 = silu_f(d * We1[j4 + 0] + be1[j4 + 0]);
        float s1 = silu_f(d * We1[j4 + 1] + be1[j4 + 1]);
        float s2 = silu_f(d * We1[j4 + 2] + be1[j4 + 2]);
        float s3 = silu_f(d * We1[j4 + 3] + be1[j4 + 3]);
        *(uint2*)&smA[e * ASTR + 2 * NODE_DIM + j4] = make_uint2(pkbf(s0, s1), pkbf(s2, s3));
    }
    __syncthreads();

    // ---- 3. GEMM1: [64 x 288] @ [288 x 512]; 2 e-tiles x 2 n-tiles; prefetch-2 ----
    f32x16 a00, a01, a10, a11;
    {
        int nb = wv * 64 + lo;
        float b0 = biasC[nb], b1 = biasC[nb + 32];
        #pragma unroll
        for (int r = 0; r < 16; ++r) { a00[r] = b0; a01[r] = b1; a10[r] = b0; a11[r] = b1; }
    }
    {
        const int aoff0 = lo * ASTR + hi * 8;
        const int aoff1 = (32 + lo) * ASTR + hi * 8;
        const int TS = 18 * 64 * 8;
        const int base = ((wv * 2 * 18) * 64 + lane) * 8;
        bf16x8 b0s[3], b1s[3];
        b0s[0] = *(const bf16x8*)&W1s[base];
        b1s[0] = *(const bf16x8*)&W1s[base + TS];
        b0s[1] = *(const bf16x8*)&W1s[base + 512];
        b1s[1] = *(const bf16x8*)&W1s[base + 512 + TS];
        #pragma unroll
        for (int step = 0; step < 18; ++step) {
            const int cur = step % 3;
            if (step + 2 < 18) {
                const int pf = (step + 2) % 3;
                b0s[pf] = *(const bf16x8*)&W1s[base + (step + 2) * 512];
                b1s[pf] = *(const bf16x8*)&W1s[base + (step + 2) * 512 + TS];
            }
            bf16x8 f0 = *(const bf16x8*)&smA[aoff0 + step * 16];
            bf16x8 f1 = *(const bf16x8*)&smA[aoff1 + step * 16];
            a00 = __builtin_amdgcn_mfma_f32_32x32x16_bf16(f0, b0s[cur], a00, 0, 0, 0);
            a10 = __builtin_amdgcn_mfma_f32_32x32x16_bf16(f1, b0s[cur], a10, 0, 0, 0);
            a01 = __builtin_amdgcn_mfma_f32_32x32x16_bf16(f0, b1s[cur], a01, 0, 0, 0);
            a11 = __builtin_amdgcn_mfma_f32_32x32x16_bf16(f1, b1s[cur], a11, 0, 0, 0);
        }
    }
    __syncthreads();                     // smA reads done before smH overwrite

    // ---- 4. epilogue: waves 0-3 -> silu -> smH; waves 4-7 c-path ----
    const int rowbase = 4 * hi;
    if (wv < 4) {
        int jb = wv * 64 + lo;
        #pragma unroll
        for (int r = 0; r < 16; ++r) {
            int er = (r & 3) + 8 * (r >> 2) + rowbase;
            unsigned short* row0 = &smH[er * HSTR + jb];
            unsigned short* row1 = &smH[(er + 32) * HSTR + jb];
            row0[0]  = f2bf_hu(silu_f(a00[r]));
            row0[32] = f2bf_hu(silu_f(a01[r]));
            row1[0]  = f2bf_hu(silu_f(a10[r]));
            row1[32] = f2bf_hu(silu_f(a11[r]));
        }
    } else {
        int nc = (wv - 4) * 64 + lo;
        float w0 = Wc2[nc], w1 = Wc2[nc + 32];
        float p0[16], p1[16];
        #pragma unroll
        for (int r = 0; r < 16; ++r) {
            p0[r] = silu_f(a00[r]) * w0 + silu_f(a01[r]) * w1;
            p1[r] = silu_f(a10[r]) * w0 + silu_f(a11[r]) * w1;
        }
        #pragma unroll
        for (int off = 1; off < 32; off <<= 1) {
            #pragma unroll
            for (int r = 0; r < 16; ++r) {
                p0[r] += __shfl_xor(p0[r], off);
                p1[r] += __shfl_xor(p1[r], off);
            }
        }
        if (lo == 0) {
            #pragma unroll
            for (int r = 0; r < 16; ++r) {
                int er = (r & 3) + 8 * (r >> 2) + rowbase;
                atomicAdd(&cw_s[er], p0[r]);
                atomicAdd(&cw_s[er + 32], p1[r]);
            }
        }
    }
    __syncthreads();

    // coordinate vectors (needs cw_s complete)
    if (t < TE) {
        int s = sidx[t], dn = didx[t];
        float dx = x[s * 3 + 0] - x[dn * 3 + 0];
        float dy = x[s * 3 + 1] - x[dn * 3 + 1];
        float dz = x[s * 3 + 2] - x[dn * 3 + 2];
        float len = fmaxf(sqrtf(dx * dx + dy * dy + dz * dz), 1e-8f);
        float w = cw_s[t] / len;
        cxyz[t] = w * dx; cxyz[TE + t] = w * dy; cxyz[2 * TE + t] = w * dz;
    }

    // ---- 5. GEMM2: [64 x 256] @ [256 x 128]; wave: (e-tile, d-tile); prefetch-2 ----
    {
        const int et = wv >> 2;
        const int dt = wv & 3;
        const int d = dt * 32 + lo;
        f32x16 acc;
        float bb = bn2[d];
        #pragma unroll
        for (int r = 0; r < 16; ++r) acc[r] = bb;
        const int hoff = (et * 32 + lo) * HSTR + hi * 8;
        const int wb = ((dt * 16) * 64 + lane) * 8;
        bf16x8 bs[3];
        bs[0] = *(const bf16x8*)&W2s[wb];
        bs[1] = *(const bf16x8*)&W2s[wb + 512];
        #pragma unroll
        for (int step = 0; step < 16; ++step) {
            const int cur = step % 3;
            if (step + 2 < 16) {
                const int pf = (step + 2) % 3;
                bs[pf] = *(const bf16x8*)&W2s[wb + (step + 2) * 512];
            }
            bf16x8 af = *(const bf16x8*)&smH[hoff + step * 16];
            acc = __builtin_amdgcn_mfma_f32_32x32x16_bf16(af, bs[cur], acc, 0, 0, 0);
        }
        __syncthreads();                 // smH reads done before smM overwrite
        #pragma unroll
        for (int r = 0; r < 16; ++r) {
            int er = et * 32 + (r & 3) + 8 * (r >> 2) + rowbase;
            smM[er * MSTR + d] = acc[r];
        }
    }
    __syncthreads();

    // ---- 6. run-reduction over sorted dst + sparse atomics ----
    {
        const int g = t >> 5;            // 16 edge-strided groups
        const int d4 = (t & 31) * 4;
        for (int e0 = g; e0 < TE; e0 += 16) {
            if (e0 > 0 && didx[e0] == didx[e0 - 1]) continue;   // not a run leader
            float4 s = *(const float4*)&smM[e0 * MSTR + d4];
            int er = e0 + 1;
            while (er < TE && didx[er] == didx[e0]) {
                float4 v = *(const float4*)&smM[er * MSTR + d4];
                s.x += v.x; s.y += v.y; s.z += v.z; s.w += v.w;
                ++er;
            }
            float* dp = &out[didx[e0] * NODE_DIM + d4];
            atomicAdd(dp + 0, s.x); atomicAdd(dp + 1, s.y);
            atomicAdd(dp + 2, s.z); atomicAdd(dp + 3, s.w);
        }
    }
    if (t < TE) {
        int e0 = t;
        if (e0 == 0 || didx[e0] != didx[e0 - 1]) {
            float sx = cxyz[e0], sy = cxyz[TE + e0], sz = cxyz[2 * TE + e0];
            int er = e0 + 1;
            while (er < TE && didx[er] == didx[e0]) {
                sx += cxyz[er]; sy += cxyz[TE + er]; sz += cxyz[2 * TE + er];
                ++er;
            }
            float* xo = out + N_NODES * NODE_DIM + didx[e0] * 3;
            atomicAdd(xo + 0, sx); atomicAdd(xo + 1, sy); atomicAdd(xo + 2, sz);
        }
    }
}

extern "C" void kernel_launch(void* const* d_in, const int* in_sizes, int n_in,
                              void* d_out, int out_size, void* d_ws, size_t ws_size,
                              hipStream_t stream) {
    const float* h    = (const float*)d_in[0];
    const float* x    = (const float*)d_in[1];
    const void*  ei   = d_in[2];
    const float* dist = (const float*)d_in[3];
    const float* We1  = (const float*)d_in[4];
    const float* be1  = (const float*)d_in[5];
    const float* We2  = (const float*)d_in[6];
    const float* be2  = (const float*)d_in[7];
    const float* Wn1  = (const float*)d_in[8];
    const float* bn1  = (const float*)d_in[9];
    const float* Wn2  = (const float*)d_in[10];
    const float* bn2  = (const float*)d_in[11];
    const float* Wc1  = (const float*)d_in[12];
    const float* bc1  = (const float*)d_in[13];
    const float* Wc2  = (const float*)d_in[14];
    float* out = (float*)d_out;

    float* biasC = (float*)((char*)d_ws + WS_BIAS_OFF);
    unsigned short* W1s = (unsigned short*)((char*)d_ws + WS_W1S_OFF);
    unsigned short* W2s = (unsigned short*)((char*)d_ws + WS_W2S_OFF);
    int* counts = (int*)((char*)d_ws + WS_CNT_OFF);
    int* cursor = (int*)((char*)d_ws + WS_CUR_OFF);
    int* perm   = (int*)((char*)d_ws + WS_PERM_OFF);
    unsigned short* hbf = (ws_size >= (size_t)WS_HBF_END)
                        ? (unsigned short*)((char*)d_ws + WS_HBF_OFF) : nullptr;

    prep_all_kernel<<<PREP_TOT / 256, 256, 0, stream>>>(
        h, x, We2, be2, Wn1, bn1, Wn2, Wc1, bc1,
        out, biasC, W1s, W2s, counts, hbf);

    hist_kernel<<<N_EDGES / 256, 256, 0, stream>>>(ei, counts);
    scan_kernel<<<1, 1024, 0, stream>>>(counts, cursor);
    place_kernel<<<N_EDGES / 256, 256, 0, stream>>>(ei, cursor, perm);

    egnn_mfma_kernel<<<N_EDGES / TE, 512, 0, stream>>>(
        h, x, ei, dist, We1, be1, bn2, Wc2, biasC, W1s, W2s, perm, hbf, out);
}

// Round 9
// 507.973 us; speedup vs baseline: 1.0061x; 1.0061x over previous
//
#include <hip/hip_runtime.h>
#include <math.h>

#define N_NODES 32768
#define N_EDGES 524288
#define NODE_DIM 128
#define HIDDEN 256
#define EDGE_DIM 32
#define TE 64              // edges per block
#define ASTR 296           // smA row stride (bf16): 592 B, 16B-aligned
#define HSTR 520           // smH row stride (bf16): 1040 B, 16B-aligned; cols 0..511 used

typedef __attribute__((ext_vector_type(8))) short bf16x8;
typedef __attribute__((ext_vector_type(16))) float f32x16;

__device__ __forceinline__ float silu_f(float v) {
    float e = __expf(-v);
    return v * __builtin_amdgcn_rcpf(1.0f + e);
}

__device__ __forceinline__ unsigned short f2bf_rne(float f) {
    union { float f; unsigned int u; } v; v.f = f;
    return (unsigned short)((v.u + 0x7fffu + ((v.u >> 16) & 1u)) >> 16);
}
__device__ __forceinline__ unsigned int pk_rne(float a, float b) {
    return (unsigned int)f2bf_rne(a) | ((unsigned int)f2bf_rne(b) << 16);
}
// half-up pack of two floats -> (bf16(a) | bf16(b)<<16)
__device__ __forceinline__ unsigned int pkbf(float a, float b) {
    union { float f; unsigned int u; } ua, ub; ua.f = a; ub.f = b;
    return __builtin_amdgcn_perm(ub.u + 0x8000u, ua.u + 0x8000u, 0x07060302u);
}
__device__ __forceinline__ unsigned short f2bf_hu(float f) {
    union { float f; unsigned int u; } v; v.f = f;
    return (unsigned short)((v.u + 0x8000u) >> 16);
}
__device__ __forceinline__ float bflo(unsigned int u) {
    union { unsigned int u; float f; } v; v.u = u << 16; return v.f;
}
__device__ __forceinline__ float bfhi(unsigned int u) {
    union { unsigned int u; float f; } v; v.u = u & 0xffff0000u; return v.f;
}

// uniform idx-width check: lanes sample the first 64 high words of ei.
__device__ __forceinline__ int detect_is64(const void* ei, int t) {
    const unsigned int* ew = (const unsigned int*)ei;
    unsigned int hiw = ew[2 * (t & 63) + 1];
    return (__ballot(hiw != 0u) == 0ULL) ? 1 : 0;
}

// ws layout (bytes)
#define WS_BIAS_OFF 1024
#define WS_W1S_OFF  69632
#define WS_W2S_OFF  364544
#define WS_CNT_OFF  430080
#define WS_CUR_OFF  561152
#define WS_PERM_OFF 692224
#define WS_HBF_OFF  2789376
#define WS_HBF_END  (WS_HBF_OFF + N_NODES * NODE_DIM * 2)

#define SEG_CNT  32768
#define SEG_W1S  147456
#define SEG_W2S  32768
#define SEG_BIAS 512
#define SEG_OUT  1073152
#define SEG_HBF  524288
#define PREP_TOT (SEG_CNT + SEG_W1S + SEG_W2S + SEG_BIAS + SEG_OUT + SEG_HBF)

__global__ void prep_all_kernel(const float* __restrict__ h, const float* __restrict__ x,
                                const float* __restrict__ We2, const float* __restrict__ be2,
                                const float* __restrict__ Wn1, const float* __restrict__ bn1,
                                const float* __restrict__ Wn2,
                                const float* __restrict__ Wc1, const float* __restrict__ bc1,
                                float* __restrict__ out, float* __restrict__ biasC,
                                unsigned short* __restrict__ W1s, unsigned short* __restrict__ W2s,
                                int* __restrict__ counts, unsigned short* __restrict__ hbf) {
    int i = blockIdx.x * 256 + threadIdx.x;
    if (i < SEG_CNT) { counts[i] = 0; return; }
    i -= SEG_CNT;
    if (i < SEG_W1S) {
        int jj = i & 7, ln = (i >> 3) & 63, rest = i >> 9;
        int step = rest % 18, tile = rest / 18;
        int n = tile * 32 + (ln & 31);
        int k = step * 16 + ((ln >> 5) * 8) + jj;
        float v;
        if (k < 256) {
            v = (n < 256) ? Wn1[k * 256 + n] : Wc1[k * 256 + (n - 256)];
        } else {
            int j = k - 256;
            float s = 0.0f;
            #pragma unroll 8
            for (int q = 0; q < 32; ++q)
                s += We2[j * 32 + q] * ((n < 256) ? Wn1[(256 + q) * 256 + n]
                                                  : Wc1[(256 + q) * 256 + (n - 256)]);
            v = s;
        }
        W1s[i] = f2bf_rne(v);
        return;
    }
    i -= SEG_W1S;
    if (i < SEG_W2S) {
        int jj = i & 7, ln = (i >> 3) & 63, rest = i >> 9;
        int step = rest & 15, tile = rest >> 4;
        int d = tile * 32 + (ln & 31);
        int k = step * 16 + ((ln >> 5) * 8) + jj;
        W2s[i] = f2bf_rne(Wn2[k * 128 + d]);
        return;
    }
    i -= SEG_W2S;
    if (i < SEG_BIAS) {
        int n = i;
        float s = (n < 256) ? bn1[n] : bc1[n - 256];
        #pragma unroll 8
        for (int q = 0; q < 32; ++q)
            s += be2[q] * ((n < 256) ? Wn1[(256 + q) * 256 + n]
                                     : Wc1[(256 + q) * 256 + (n - 256)]);
        biasC[n] = s;
        return;
    }
    i -= SEG_BIAS;
    if (i < SEG_OUT) {
        const int NH4 = N_NODES * NODE_DIM / 4;
        const float4* h4 = (const float4*)h;
        const float4* x4 = (const float4*)x;
        ((float4*)out)[i] = (i < NH4) ? h4[i] : x4[i - NH4];
        return;
    }
    i -= SEG_OUT;
    if (hbf != nullptr && i < SEG_HBF) {
        const float4* p = (const float4*)&h[i * 8];
        float4 v0 = p[0], v1 = p[1];
        uint4 o = make_uint4(pk_rne(v0.x, v0.y), pk_rne(v0.z, v0.w),
                             pk_rne(v1.x, v1.y), pk_rne(v1.z, v1.w));
        *(uint4*)&hbf[i * 8] = o;
    }
}

__global__ void hist_kernel(const void* __restrict__ ei, int* __restrict__ counts) {
    int is64 = detect_is64(ei, threadIdx.x);
    int e = blockIdx.x * 256 + threadIdx.x;
    int dst = is64 ? (int)((const long long*)ei)[N_EDGES + e]
                   : ((const int*)ei)[N_EDGES + e];
    atomicAdd(&counts[dst], 1);
}

__global__ __launch_bounds__(1024)
void scan_kernel(const int* __restrict__ counts, int* __restrict__ cursor) {
    __shared__ int part[1024];
    const int t = threadIdx.x;
    const int base = t * 32;
    int loc[32];
    int s = 0;
    #pragma unroll
    for (int i = 0; i < 32; ++i) { loc[i] = s; s += counts[base + i]; }
    part[t] = s;
    __syncthreads();
    #pragma unroll
    for (int d = 1; d < 1024; d <<= 1) {
        int v = (t >= d) ? part[t - d] : 0;
        __syncthreads();
        part[t] += v;
        __syncthreads();
    }
    int excl = part[t] - s;
    #pragma unroll
    for (int i = 0; i < 32; ++i) cursor[base + i] = excl + loc[i];
}

__global__ void place_kernel(const void* __restrict__ ei,
                             int* __restrict__ cursor, int* __restrict__ perm) {
    int is64 = detect_is64(ei, threadIdx.x);
    int e = blockIdx.x * 256 + threadIdx.x;
    int dst = is64 ? (int)((const long long*)ei)[N_EDGES + e]
                   : ((const int*)ei)[N_EDGES + e];
    int pos = atomicAdd(&cursor[dst], 1);
    perm[pos] = e;
}

__global__ __launch_bounds__(512, 4)
void egnn_mfma_kernel(const float* __restrict__ h, const float* __restrict__ x,
                      const void* __restrict__ ei, const float* __restrict__ dist,
                      const float* __restrict__ We1, const float* __restrict__ be1,
                      const float* __restrict__ bn2, const float* __restrict__ Wc2,
                      const float* __restrict__ biasC,
                      const unsigned short* __restrict__ W1s,
                      const unsigned short* __restrict__ W2s,
                      const int* __restrict__ perm,
                      const unsigned short* __restrict__ hbf,
                      float* __restrict__ out)
{
    // one region: smA [64][296] (GEMM1 A) -> smH [64][520] (silu n|c) -> smM over cols 0..127
    __shared__ __attribute__((aligned(16))) unsigned short smArr[TE * HSTR];   // 66560 B
    __shared__ __attribute__((aligned(16))) int didx[TE];
    __shared__ int sidx[TE], eidx[TE];
    __shared__ float cxyz[3 * TE];

    unsigned short* smA = smArr;
    unsigned short* smH = smArr;

    const int t = threadIdx.x;
    const int lane = t & 63;
    const int wv = t >> 6;       // 0..7
    const int lo = lane & 31;
    const int hi = lane >> 5;
    const int ebase = blockIdx.x * TE;
    const int is64 = detect_is64(ei, t);

    // ---- P1. permuted edge indices ----
    if (t < 2 * TE) {
        int e = t & (TE - 1);
        int eid = perm[ebase + e];
        int which = t >> 6;              // 0 = src, 1 = dst
        long long pos = (long long)which * N_EDGES + eid;
        int idx = is64 ? (int)((const long long*)ei)[pos] : ((const int*)ei)[pos];
        if (which == 0) { sidx[e] = idx; eidx[e] = eid; }
        else didx[e] = idx;
    }
    __syncthreads();

    // ---- P2a. gather h[src], h[dst] -> bf16 smA ----
    if (hbf != nullptr) {
        #pragma unroll
        for (int it = 0; it < 4; ++it) {
            int id = it * 512 + t;
            int g = id & 15;
            int half = (id >> 4) & 1;
            int e = id >> 5;
            int node = half ? didx[e] : sidx[e];
            uint4 v = *(const uint4*)&hbf[node * NODE_DIM + 8 * g];
            *(uint4*)&smA[e * ASTR + half * NODE_DIM + 8 * g] = v;
        }
    } else {
        #pragma unroll
        for (int it = 0; it < 4; ++it) {
            int id = it * 512 + t;
            int g8 = id & 15;
            int half = (id >> 4) & 1;
            int e = id >> 5;
            int node = half ? didx[e] : sidx[e];
            const float4* p = (const float4*)&h[node * NODE_DIM + 8 * g8];
            float4 v0 = p[0], v1 = p[1];
            unsigned int a0 = pkbf(v0.x, v0.y), a1 = pkbf(v0.z, v0.w);
            unsigned int a2 = pkbf(v1.x, v1.y), a3 = pkbf(v1.z, v1.w);
            *(uint4*)&smA[e * ASTR + half * NODE_DIM + 8 * g8] = make_uint4(a0, a1, a2, a3);
        }
    }
    // ---- P2b. t1 = silu(d*We1+be1) -> smA[:,256:288] ----
    {
        int e = t >> 3;
        int j4 = (t & 7) * 4;
        float d = dist[eidx[e]];
        float s0 = silu_f(d * We1[j4 + 0] + be1[j4 + 0]);
        float s1 = silu_f(d * We1[j4 + 1] + be1[j4 + 1]);
        float s2 = silu_f(d * We1[j4 + 2] + be1[j4 + 2]);
        float s3 = silu_f(d * We1[j4 + 3] + be1[j4 + 3]);
        *(uint2*)&smA[e * ASTR + 2 * NODE_DIM + j4] = make_uint2(pkbf(s0, s1), pkbf(s2, s3));
    }
    __syncthreads();

    // ---- P3. GEMM1: [64 x 288] @ [288 x 512]; 2 e-tiles x 2 n-tiles; prefetch-2 ----
    f32x16 a00, a01, a10, a11;
    {
        int nb = wv * 64 + lo;
        float b0 = biasC[nb], b1 = biasC[nb + 32];
        #pragma unroll
        for (int r = 0; r < 16; ++r) { a00[r] = b0; a01[r] = b1; a10[r] = b0; a11[r] = b1; }
    }
    {
        const int aoff0 = lo * ASTR + hi * 8;
        const int aoff1 = (32 + lo) * ASTR + hi * 8;
        const int TS = 18 * 64 * 8;
        const int base = ((wv * 2 * 18) * 64 + lane) * 8;
        bf16x8 b0s[3], b1s[3];
        b0s[0] = *(const bf16x8*)&W1s[base];
        b1s[0] = *(const bf16x8*)&W1s[base + TS];
        b0s[1] = *(const bf16x8*)&W1s[base + 512];
        b1s[1] = *(const bf16x8*)&W1s[base + 512 + TS];
        #pragma unroll
        for (int step = 0; step < 18; ++step) {
            const int cur = step % 3;
            if (step + 2 < 18) {
                const int pf = (step + 2) % 3;
                b0s[pf] = *(const bf16x8*)&W1s[base + (step + 2) * 512];
                b1s[pf] = *(const bf16x8*)&W1s[base + (step + 2) * 512 + TS];
            }
            bf16x8 f0 = *(const bf16x8*)&smA[aoff0 + step * 16];
            bf16x8 f1 = *(const bf16x8*)&smA[aoff1 + step * 16];
            a00 = __builtin_amdgcn_mfma_f32_32x32x16_bf16(f0, b0s[cur], a00, 0, 0, 0);
            a10 = __builtin_amdgcn_mfma_f32_32x32x16_bf16(f1, b0s[cur], a10, 0, 0, 0);
            a01 = __builtin_amdgcn_mfma_f32_32x32x16_bf16(f0, b1s[cur], a01, 0, 0, 0);
            a11 = __builtin_amdgcn_mfma_f32_32x32x16_bf16(f1, b1s[cur], a11, 0, 0, 0);
        }
    }
    __syncthreads();                     // smA reads done before smH overwrite

    // ---- P4. epilogue (symmetric, all 8 waves): silu -> smH[e][wv*64+lo(+32)] ----
    const int rowbase = 4 * hi;
    {
        const int jb = wv * 64 + lo;
        #pragma unroll
        for (int r = 0; r < 16; ++r) {
            int er = (r & 3) + 8 * (r >> 2) + rowbase;
            unsigned short* row0 = &smH[er * HSTR + jb];
            unsigned short* row1 = &smH[(er + 32) * HSTR + jb];
            row0[0]  = f2bf_hu(silu_f(a00[r]));
            row0[32] = f2bf_hu(silu_f(a01[r]));
            row1[0]  = f2bf_hu(silu_f(a10[r]));
            row1[32] = f2bf_hu(silu_f(a11[r]));
        }
    }
    __syncthreads();

    // ---- P5. GEMM2 [64x256]@[256x128] (smH cols 0..255) + cw-dot (cols 256..511) ----
    f32x16 acc;
    {
        const int et = wv >> 2;
        const int dt = wv & 3;
        const int d = dt * 32 + lo;
        float bb = bn2[d];
        #pragma unroll
        for (int r = 0; r < 16; ++r) acc[r] = bb;
        const int hoff = (et * 32 + lo) * HSTR + hi * 8;
        const int wb = ((dt * 16) * 64 + lane) * 8;
        bf16x8 bs[3];
        bs[0] = *(const bf16x8*)&W2s[wb];
        bs[1] = *(const bf16x8*)&W2s[wb + 512];
        #pragma unroll
        for (int step = 0; step < 16; ++step) {
            const int cur = step % 3;
            if (step + 2 < 16) {
                const int pf = (step + 2) % 3;
                bs[pf] = *(const bf16x8*)&W2s[wb + (step + 2) * 512];
            }
            bf16x8 af = *(const bf16x8*)&smH[hoff + step * 16];
            acc = __builtin_amdgcn_mfma_f32_32x32x16_bf16(af, bs[cur], acc, 0, 0, 0);
        }
    }
    // cw-dot in the MFMA shadow: e = t>>3 (8 threads/edge), chunk c = t&7 (32 c-cols)
    float cw;
    {
        const int e = t >> 3;
        const int c0 = (t & 7) * 32;
        const unsigned short* hrow = &smH[e * HSTR + 256 + c0];
        float s = 0.0f;
        #pragma unroll
        for (int j = 0; j < 4; ++j) {
            uint4 q = *(const uint4*)&hrow[j * 8];
            float4 w0 = *(const float4*)&Wc2[c0 + j * 8];
            float4 w1 = *(const float4*)&Wc2[c0 + j * 8 + 4];
            s += bflo(q.x) * w0.x + bfhi(q.x) * w0.y + bflo(q.y) * w0.z + bfhi(q.y) * w0.w;
            s += bflo(q.z) * w1.x + bfhi(q.z) * w1.y + bflo(q.w) * w1.z + bfhi(q.w) * w1.w;
        }
        s += __shfl_xor(s, 1);
        s += __shfl_xor(s, 2);
        s += __shfl_xor(s, 4);
        cw = s;                           // valid on all 8 lanes of the edge-group
        if ((t & 7) == 0) {
            int sn = sidx[e], dn = didx[e];
            float dx = x[sn * 3 + 0] - x[dn * 3 + 0];
            float dy = x[sn * 3 + 1] - x[dn * 3 + 1];
            float dz = x[sn * 3 + 2] - x[dn * 3 + 2];
            float len = fmaxf(sqrtf(dx * dx + dy * dy + dz * dz), 1e-8f);
            float w = cw * __builtin_amdgcn_rcpf(len);
            // rcp is approx; refine with one NR step for safety: w = cw/len
            w = cw / len;
            cxyz[e] = w * dx; cxyz[TE + e] = w * dy; cxyz[2 * TE + e] = w * dz;
        }
    }
    __syncthreads();                     // GEMM2 smH reads + cw reads done

    // smM overlays cols 0..127 (f32) of each smH row
    {
        const int et = wv >> 2;
        const int dt = wv & 3;
        const int d = dt * 32 + lo;
        #pragma unroll
        for (int r = 0; r < 16; ++r) {
            int er = et * 32 + (r & 3) + 8 * (r >> 2) + rowbase;
            *(float*)&smArr[er * HSTR + 2 * d] = acc[r];
        }
    }
    __syncthreads();

    // ---- P6. run-reduction over sorted dst + sparse atomics ----
    {
        const int g = t >> 5;            // 16 edge-strided groups
        const int d4 = (t & 31) * 4;
        for (int e0 = g; e0 < TE; e0 += 16) {
            if (e0 > 0 && didx[e0] == didx[e0 - 1]) continue;   // not a run leader
            float4 s = *(const float4*)&smArr[e0 * HSTR + 2 * d4];
            int er = e0 + 1;
            while (er < TE && didx[er] == didx[e0]) {
                float4 v = *(const float4*)&smArr[er * HSTR + 2 * d4];
                s.x += v.x; s.y += v.y; s.z += v.z; s.w += v.w;
                ++er;
            }
            float* dp = &out[didx[e0] * NODE_DIM + d4];
            atomicAdd(dp + 0, s.x); atomicAdd(dp + 1, s.y);
            atomicAdd(dp + 2, s.z); atomicAdd(dp + 3, s.w);
        }
    }
    if (t < TE) {
        int e0 = t;
        if (e0 == 0 || didx[e0] != didx[e0 - 1]) {
            float sx = cxyz[e0], sy = cxyz[TE + e0], sz = cxyz[2 * TE + e0];
            int er = e0 + 1;
            while (er < TE && didx[er] == didx[e0]) {
                sx += cxyz[er]; sy += cxyz[TE + er]; sz += cxyz[2 * TE + er];
                ++er;
            }
            float* xo = out + N_NODES * NODE_DIM + didx[e0] * 3;
            atomicAdd(xo + 0, sx); atomicAdd(xo + 1, sy); atomicAdd(xo + 2, sz);
        }
    }
}

extern "C" void kernel_launch(void* const* d_in, const int* in_sizes, int n_in,
                              void* d_out, int out_size, void* d_ws, size_t ws_size,
                              hipStream_t stream) {
    const float* h    = (const float*)d_in[0];
    const float* x    = (const float*)d_in[1];
    const void*  ei   = d_in[2];
    const float* dist = (const float*)d_in[3];
    const float* We1  = (const float*)d_in[4];
    const float* be1  = (const float*)d_in[5];
    const float* We2  = (const float*)d_in[6];
    const float* be2  = (const float*)d_in[7];
    const float* Wn1  = (const float*)d_in[8];
    const float* bn1  = (const float*)d_in[9];
    const float* Wn2  = (const float*)d_in[10];
    const float* bn2  = (const float*)d_in[11];
    const float* Wc1  = (const float*)d_in[12];
    const float* bc1  = (const float*)d_in[13];
    const float* Wc2  = (const float*)d_in[14];
    float* out = (float*)d_out;

    float* biasC = (float*)((char*)d_ws + WS_BIAS_OFF);
    unsigned short* W1s = (unsigned short*)((char*)d_ws + WS_W1S_OFF);
    unsigned short* W2s = (unsigned short*)((char*)d_ws + WS_W2S_OFF);
    int* counts = (int*)((char*)d_ws + WS_CNT_OFF);
    int* cursor = (int*)((char*)d_ws + WS_CUR_OFF);
    int* perm   = (int*)((char*)d_ws + WS_PERM_OFF);
    unsigned short* hbf = (ws_size >= (size_t)WS_HBF_END)
                        ? (unsigned short*)((char*)d_ws + WS_HBF_OFF) : nullptr;

    prep_all_kernel<<<PREP_TOT / 256, 256, 0, stream>>>(
        h, x, We2, be2, Wn1, bn1, Wn2, Wc1, bc1,
        out, biasC, W1s, W2s, counts, hbf);

    hist_kernel<<<N_EDGES / 256, 256, 0, stream>>>(ei, counts);
    scan_kernel<<<1, 1024, 0, stream>>>(counts, cursor);
    place_kernel<<<N_EDGES / 256, 256, 0, stream>>>(ei, cursor, perm);

    egnn_mfma_kernel<<<N_EDGES / TE, 512, 0, stream>>>(
        h, x, ei, dist, We1, be1, bn2, Wc2, biasC, W1s, W2s, perm, hbf, out);
}

// Round 10
// 479.674 us; speedup vs baseline: 1.0655x; 1.0590x over previous
//
#include <hip/hip_runtime.h>
#include <math.h>

#define N_NODES 32768
#define N_EDGES 524288
#define NODE_DIM 128
#define HIDDEN 256
#define EDGE_DIM 32
#define TE 64              // edges per block
#define ASTR 296           // smA row stride (bf16): 592 B, 16B-aligned
#define HSTR 264           // smH row stride (bf16): 528 B, 16B-aligned
#define MSTR 132           // smM row stride (f32): 528 B, 16B-aligned

typedef __attribute__((ext_vector_type(8))) short bf16x8;
typedef __attribute__((ext_vector_type(16))) float f32x16;

__device__ __forceinline__ float silu_f(float v) {
    float e = __expf(-v);
    return v * __builtin_amdgcn_rcpf(1.0f + e);
}

__device__ __forceinline__ unsigned short f2bf_rne(float f) {
    union { float f; unsigned int u; } v; v.f = f;
    return (unsigned short)((v.u + 0x7fffu + ((v.u >> 16) & 1u)) >> 16);
}
__device__ __forceinline__ unsigned int pk_rne(float a, float b) {
    return (unsigned int)f2bf_rne(a) | ((unsigned int)f2bf_rne(b) << 16);
}
// half-up pack of two floats -> (bf16(a) | bf16(b)<<16)
__device__ __forceinline__ unsigned int pkbf(float a, float b) {
    union { float f; unsigned int u; } ua, ub; ua.f = a; ub.f = b;
    return __builtin_amdgcn_perm(ub.u + 0x8000u, ua.u + 0x8000u, 0x07060302u);
}
__device__ __forceinline__ unsigned short f2bf_hu(float f) {
    union { float f; unsigned int u; } v; v.f = f;
    return (unsigned short)((v.u + 0x8000u) >> 16);
}

// uniform idx-width check: lanes sample the first 64 high words of ei.
__device__ __forceinline__ int detect_is64(const void* ei, int t) {
    const unsigned int* ew = (const unsigned int*)ei;
    unsigned int hiw = ew[2 * (t & 63) + 1];
    return (__ballot(hiw != 0u) == 0ULL) ? 1 : 0;
}

// ws layout (bytes)
#define WS_BIAS_OFF 1024
#define WS_W1S_OFF  69632
#define WS_W2S_OFF  364544
#define WS_CNT_OFF  430080
#define WS_CUR_OFF  561152
#define WS_PERM_OFF 692224
#define WS_PART_OFF 2789376
#define WS_HBF_OFF  2790400
#define WS_HBF_END  (WS_HBF_OFF + N_NODES * NODE_DIM * 2)

#define SEG_CNT  32768
#define SEG_W1S  147456
#define SEG_W2S  32768
#define SEG_BIAS 512
#define SEG_OUT  1073152
#define SEG_HBF  524288
#define PREP_TOT (SEG_CNT + SEG_W1S + SEG_W2S + SEG_BIAS + SEG_OUT + SEG_HBF)

__global__ void prep_all_kernel(const float* __restrict__ h, const float* __restrict__ x,
                                const float* __restrict__ We2, const float* __restrict__ be2,
                                const float* __restrict__ Wn1, const float* __restrict__ bn1,
                                const float* __restrict__ Wn2,
                                const float* __restrict__ Wc1, const float* __restrict__ bc1,
                                float* __restrict__ out, float* __restrict__ biasC,
                                unsigned short* __restrict__ W1s, unsigned short* __restrict__ W2s,
                                int* __restrict__ counts, unsigned short* __restrict__ hbf) {
    int i = blockIdx.x * 256 + threadIdx.x;
    if (i < SEG_CNT) { counts[i] = 0; return; }
    i -= SEG_CNT;
    if (i < SEG_W1S) {
        // B-frag order: idx = ((tile*18+step)*64+lane)*8+jj ; n = tile*32+(lane&31);
        // k = step*16+(lane>>5)*8+jj ; edge-MLP layer 2 folded for k >= 256
        int jj = i & 7, ln = (i >> 3) & 63, rest = i >> 9;
        int step = rest % 18, tile = rest / 18;
        int n = tile * 32 + (ln & 31);
        int k = step * 16 + ((ln >> 5) * 8) + jj;
        float v;
        if (k < 256) {
            v = (n < 256) ? Wn1[k * 256 + n] : Wc1[k * 256 + (n - 256)];
        } else {
            int j = k - 256;
            float s = 0.0f;
            #pragma unroll 8
            for (int q = 0; q < 32; ++q)
                s += We2[j * 32 + q] * ((n < 256) ? Wn1[(256 + q) * 256 + n]
                                                  : Wc1[(256 + q) * 256 + (n - 256)]);
            v = s;
        }
        W1s[i] = f2bf_rne(v);
        return;
    }
    i -= SEG_W1S;
    if (i < SEG_W2S) {
        int jj = i & 7, ln = (i >> 3) & 63, rest = i >> 9;
        int step = rest & 15, tile = rest >> 4;
        int d = tile * 32 + (ln & 31);
        int k = step * 16 + ((ln >> 5) * 8) + jj;
        W2s[i] = f2bf_rne(Wn2[k * 128 + d]);
        return;
    }
    i -= SEG_W2S;
    if (i < SEG_BIAS) {
        int n = i;
        float s = (n < 256) ? bn1[n] : bc1[n - 256];
        #pragma unroll 8
        for (int q = 0; q < 32; ++q)
            s += be2[q] * ((n < 256) ? Wn1[(256 + q) * 256 + n]
                                     : Wc1[(256 + q) * 256 + (n - 256)]);
        biasC[n] = s;
        return;
    }
    i -= SEG_BIAS;
    if (i < SEG_OUT) {
        const int NH4 = N_NODES * NODE_DIM / 4;
        const float4* h4 = (const float4*)h;
        const float4* x4 = (const float4*)x;
        ((float4*)out)[i] = (i < NH4) ? h4[i] : x4[i - NH4];
        return;
    }
    i -= SEG_OUT;
    if (hbf != nullptr && i < SEG_HBF) {
        const float4* p = (const float4*)&h[i * 8];
        float4 v0 = p[0], v1 = p[1];
        uint4 o = make_uint4(pk_rne(v0.x, v0.y), pk_rne(v0.z, v0.w),
                             pk_rne(v1.x, v1.y), pk_rne(v1.z, v1.w));
        *(uint4*)&hbf[i * 8] = o;
    }
}

__global__ void hist_kernel(const void* __restrict__ ei, int* __restrict__ counts) {
    int is64 = detect_is64(ei, threadIdx.x);
    int e = blockIdx.x * 256 + threadIdx.x;
    int dst = is64 ? (int)((const long long*)ei)[N_EDGES + e]
                   : ((const int*)ei)[N_EDGES + e];
    atomicAdd(&counts[dst], 1);
}

// parallel scan stage A: 128 blocks x 256 threads; partials[b] = sum of counts[b*256 .. b*256+255]
__global__ __launch_bounds__(256)
void scanA_kernel(const int* __restrict__ counts, int* __restrict__ partials) {
    __shared__ int red[256];
    const int t = threadIdx.x;
    const int b = blockIdx.x;
    red[t] = counts[b * 256 + t];
    __syncthreads();
    #pragma unroll
    for (int s = 128; s > 0; s >>= 1) {
        if (t < s) red[t] += red[t + s];
        __syncthreads();
    }
    if (t == 0) partials[b] = red[0];
}

// parallel scan stage C: 128 blocks; each block redundantly prefixes the 128 partials
// in-LDS, then does a block-local exclusive scan of its 256 counts -> cursor.
__global__ __launch_bounds__(256)
void scanC_kernel(const int* __restrict__ counts, const int* __restrict__ partials,
                  int* __restrict__ cursor) {
    __shared__ int pb[128];
    __shared__ int loc[256];
    const int t = threadIdx.x;
    const int b = blockIdx.x;
    if (t < 128) pb[t] = partials[t];
    int c = counts[b * 256 + t];
    loc[t] = c;
    __syncthreads();
    // base = sum of partials[0..b-1] (redundant per block; 128 adds by wave 0 lanes)
    if (t == 0) {
        int s = 0;
        for (int j = 0; j < 128; ++j) { int v = pb[j]; pb[j] = s; s += v; }
    }
    // Hillis-Steele inclusive scan over 256 elements
    #pragma unroll
    for (int d = 1; d < 256; d <<= 1) {
        int v = (t >= d) ? loc[t - d] : 0;
        __syncthreads();
        loc[t] += v;
        __syncthreads();
    }
    cursor[b * 256 + t] = pb[b] + loc[t] - c;   // exclusive
}

__global__ void place_kernel(const void* __restrict__ ei,
                             int* __restrict__ cursor, int* __restrict__ perm) {
    int is64 = detect_is64(ei, threadIdx.x);
    int e = blockIdx.x * 256 + threadIdx.x;
    int dst = is64 ? (int)((const long long*)ei)[N_EDGES + e]
                   : ((const int*)ei)[N_EDGES + e];
    int pos = atomicAdd(&cursor[dst], 1);
    perm[pos] = e;
}

__global__ __launch_bounds__(512, 4)
void egnn_mfma_kernel(const float* __restrict__ h, const float* __restrict__ x,
                      const void* __restrict__ ei, const float* __restrict__ dist,
                      const float* __restrict__ We1, const float* __restrict__ be1,
                      const float* __restrict__ bn2, const float* __restrict__ Wc2,
                      const float* __restrict__ biasC,
                      const unsigned short* __restrict__ W1s,
                      const unsigned short* __restrict__ W2s,
                      const int* __restrict__ perm,
                      const unsigned short* __restrict__ hbf,
                      float* __restrict__ out)
{
    // one overlapped region: smA (GEMM1 A) -> smH (GEMM2 A) -> smM (f32 m tile)
    __shared__ unsigned short smA[TE * ASTR];          // 37888 B
    __shared__ int sidx[TE], didx[TE], eidx[TE];
    __shared__ float cw_s[TE];
    __shared__ float cxyz[3 * TE];

    unsigned short* smH = smA;
    float* smM = (float*)smA;

    const int t = threadIdx.x;
    const int lane = t & 63;
    const int wv = t >> 6;       // 0..7
    const int lo = lane & 31;
    const int hi = lane >> 5;
    const int ebase = blockIdx.x * TE;
    const int is64 = detect_is64(ei, t);

    // ---- 1. permuted edge indices + zero cw ----
    if (t < 2 * TE) {
        int e = t & (TE - 1);
        int eid = perm[ebase + e];
        int which = t >> 6;              // 0 = src, 1 = dst
        long long pos = (long long)which * N_EDGES + eid;
        int idx = is64 ? (int)((const long long*)ei)[pos] : ((const int*)ei)[pos];
        if (which == 0) { sidx[e] = idx; eidx[e] = eid; }
        else didx[e] = idx;
        if (t < TE) cw_s[t] = 0.0f;
    }
    __syncthreads();

    // ---- 2a. gather h[src], h[dst] -> bf16 smA ----
    if (hbf != nullptr) {
        #pragma unroll
        for (int it = 0; it < 4; ++it) {
            int id = it * 512 + t;
            int g = id & 15;             // 16B unit within 128-dim half
            int half = (id >> 4) & 1;
            int e = id >> 5;
            int node = half ? didx[e] : sidx[e];
            uint4 v = *(const uint4*)&hbf[node * NODE_DIM + 8 * g];
            *(uint4*)&smA[e * ASTR + half * NODE_DIM + 8 * g] = v;
        }
    } else {
        #pragma unroll
        for (int it = 0; it < 4; ++it) {
            int id = it * 512 + t;
            int g8 = id & 15;
            int half = (id >> 4) & 1;
            int e = id >> 5;
            int node = half ? didx[e] : sidx[e];
            const float4* p = (const float4*)&h[node * NODE_DIM + 8 * g8];
            float4 v0 = p[0], v1 = p[1];
            unsigned int a0 = pkbf(v0.x, v0.y), a1 = pkbf(v0.z, v0.w);
            unsigned int a2 = pkbf(v1.x, v1.y), a3 = pkbf(v1.z, v1.w);
            *(uint4*)&smA[e * ASTR + half * NODE_DIM + 8 * g8] = make_uint4(a0, a1, a2, a3);
        }
    }
    // ---- 2b. t1 = silu(d*We1+be1) -> smA[:,256:288] (layer2 folded in W1s) ----
    {
        int e = t >> 3;
        int j4 = (t & 7) * 4;
        float d = dist[eidx[e]];
        float s0 = silu_f(d * We1[j4 + 0] + be1[j4 + 0]);
        float s1 = silu_f(d * We1[j4 + 1] + be1[j4 + 1]);
        float s2 = silu_f(d * We1[j4 + 2] + be1[j4 + 2]);
        float s3 = silu_f(d * We1[j4 + 3] + be1[j4 + 3]);
        *(uint2*)&smA[e * ASTR + 2 * NODE_DIM + j4] = make_uint2(pkbf(s0, s1), pkbf(s2, s3));
    }
    __syncthreads();

    // ---- 3. GEMM1: [64 x 288] @ [288 x 512]; 2 e-tiles x 2 n-tiles; prefetch-2 ----
    f32x16 a00, a01, a10, a11;
    {
        int nb = wv * 64 + lo;
        float b0 = biasC[nb], b1 = biasC[nb + 32];
        #pragma unroll
        for (int r = 0; r < 16; ++r) { a00[r] = b0; a01[r] = b1; a10[r] = b0; a11[r] = b1; }
    }
    {
        const int aoff0 = lo * ASTR + hi * 8;
        const int aoff1 = (32 + lo) * ASTR + hi * 8;
        const int TS = 18 * 64 * 8;
        const int base = ((wv * 2 * 18) * 64 + lane) * 8;
        bf16x8 b0s[3], b1s[3];
        b0s[0] = *(const bf16x8*)&W1s[base];
        b1s[0] = *(const bf16x8*)&W1s[base + TS];
        b0s[1] = *(const bf16x8*)&W1s[base + 512];
        b1s[1] = *(const bf16x8*)&W1s[base + 512 + TS];
        #pragma unroll
        for (int step = 0; step < 18; ++step) {
            const int cur = step % 3;
            if (step + 2 < 18) {
                const int pf = (step + 2) % 3;
                b0s[pf] = *(const bf16x8*)&W1s[base + (step + 2) * 512];
                b1s[pf] = *(const bf16x8*)&W1s[base + (step + 2) * 512 + TS];
            }
            bf16x8 f0 = *(const bf16x8*)&smA[aoff0 + step * 16];
            bf16x8 f1 = *(const bf16x8*)&smA[aoff1 + step * 16];
            a00 = __builtin_amdgcn_mfma_f32_32x32x16_bf16(f0, b0s[cur], a00, 0, 0, 0);
            a10 = __builtin_amdgcn_mfma_f32_32x32x16_bf16(f1, b0s[cur], a10, 0, 0, 0);
            a01 = __builtin_amdgcn_mfma_f32_32x32x16_bf16(f0, b1s[cur], a01, 0, 0, 0);
            a11 = __builtin_amdgcn_mfma_f32_32x32x16_bf16(f1, b1s[cur], a11, 0, 0, 0);
        }
    }
    __syncthreads();                     // smA reads done before smH overwrite

    // ---- 4. epilogue: waves 0-3 -> silu -> smH; waves 4-7 c-path ----
    const int rowbase = 4 * hi;
    if (wv < 4) {
        int jb = wv * 64 + lo;
        #pragma unroll
        for (int r = 0; r < 16; ++r) {
            int er = (r & 3) + 8 * (r >> 2) + rowbase;
            unsigned short* row0 = &smH[er * HSTR + jb];
            unsigned short* row1 = &smH[(er + 32) * HSTR + jb];
            row0[0]  = f2bf_hu(silu_f(a00[r]));
            row0[32] = f2bf_hu(silu_f(a01[r]));
            row1[0]  = f2bf_hu(silu_f(a10[r]));
            row1[32] = f2bf_hu(silu_f(a11[r]));
        }
    } else {
        int nc = (wv - 4) * 64 + lo;
        float w0 = Wc2[nc], w1 = Wc2[nc + 32];
        float p0[16], p1[16];
        #pragma unroll
        for (int r = 0; r < 16; ++r) {
            p0[r] = silu_f(a00[r]) * w0 + silu_f(a01[r]) * w1;
            p1[r] = silu_f(a10[r]) * w0 + silu_f(a11[r]) * w1;
        }
        #pragma unroll
        for (int off = 1; off < 32; off <<= 1) {
            #pragma unroll
            for (int r = 0; r < 16; ++r) {
                p0[r] += __shfl_xor(p0[r], off);
                p1[r] += __shfl_xor(p1[r], off);
            }
        }
        if (lo == 0) {
            #pragma unroll
            for (int r = 0; r < 16; ++r) {
                int er = (r & 3) + 8 * (r >> 2) + rowbase;
                atomicAdd(&cw_s[er], p0[r]);
                atomicAdd(&cw_s[er + 32], p1[r]);
            }
        }
    }
    __syncthreads();

    // coordinate vectors (needs cw_s complete)
    if (t < TE) {
        int s = sidx[t], dn = didx[t];
        float dx = x[s * 3 + 0] - x[dn * 3 + 0];
        float dy = x[s * 3 + 1] - x[dn * 3 + 1];
        float dz = x[s * 3 + 2] - x[dn * 3 + 2];
        float len = fmaxf(sqrtf(dx * dx + dy * dy + dz * dz), 1e-8f);
        float w = cw_s[t] / len;
        cxyz[t] = w * dx; cxyz[TE + t] = w * dy; cxyz[2 * TE + t] = w * dz;
    }

    // ---- 5. GEMM2: [64 x 256] @ [256 x 128]; wave: (e-tile, d-tile); prefetch-2 ----
    {
        const int et = wv >> 2;
        const int dt = wv & 3;
        const int d = dt * 32 + lo;
        f32x16 acc;
        float bb = bn2[d];
        #pragma unroll
        for (int r = 0; r < 16; ++r) acc[r] = bb;
        const int hoff = (et * 32 + lo) * HSTR + hi * 8;
        const int wb = ((dt * 16) * 64 + lane) * 8;
        bf16x8 bs[3];
        bs[0] = *(const bf16x8*)&W2s[wb];
        bs[1] = *(const bf16x8*)&W2s[wb + 512];
        #pragma unroll
        for (int step = 0; step < 16; ++step) {
            const int cur = step % 3;
            if (step + 2 < 16) {
                const int pf = (step + 2) % 3;
                bs[pf] = *(const bf16x8*)&W2s[wb + (step + 2) * 512];
            }
            bf16x8 af = *(const bf16x8*)&smH[hoff + step * 16];
            acc = __builtin_amdgcn_mfma_f32_32x32x16_bf16(af, bs[cur], acc, 0, 0, 0);
        }
        __syncthreads();                 // smH reads done before smM overwrite
        #pragma unroll
        for (int r = 0; r < 16; ++r) {
            int er = et * 32 + (r & 3) + 8 * (r >> 2) + rowbase;
            smM[er * MSTR + d] = acc[r];
        }
    }
    __syncthreads();

    // ---- 6. run-reduction over sorted dst + sparse atomics ----
    {
        const int g = t >> 5;            // 16 edge-strided groups
        const int d4 = (t & 31) * 4;
        for (int e0 = g; e0 < TE; e0 += 16) {
            if (e0 > 0 && didx[e0] == didx[e0 - 1]) continue;   // not a run leader
            float4 s = *(const float4*)&smM[e0 * MSTR + d4];
            int er = e0 + 1;
            while (er < TE && didx[er] == didx[e0]) {
                float4 v = *(const float4*)&smM[er * MSTR + d4];
                s.x += v.x; s.y += v.y; s.z += v.z; s.w += v.w;
                ++er;
            }
            float* dp = &out[didx[e0] * NODE_DIM + d4];
            atomicAdd(dp + 0, s.x); atomicAdd(dp + 1, s.y);
            atomicAdd(dp + 2, s.z); atomicAdd(dp + 3, s.w);
        }
    }
    if (t < TE) {
        int e0 = t;
        if (e0 == 0 || didx[e0] != didx[e0 - 1]) {
            float sx = cxyz[e0], sy = cxyz[TE + e0], sz = cxyz[2 * TE + e0];
            int er = e0 + 1;
            while (er < TE && didx[er] == didx[e0]) {
                sx += cxyz[er]; sy += cxyz[TE + er]; sz += cxyz[2 * TE + er];
                ++er;
            }
            float* xo = out + N_NODES * NODE_DIM + didx[e0] * 3;
            atomicAdd(xo + 0, sx); atomicAdd(xo + 1, sy); atomicAdd(xo + 2, sz);
        }
    }
}

extern "C" void kernel_launch(void* const* d_in, const int* in_sizes, int n_in,
                              void* d_out, int out_size, void* d_ws, size_t ws_size,
                              hipStream_t stream) {
    const float* h    = (const float*)d_in[0];
    const float* x    = (const float*)d_in[1];
    const void*  ei   = d_in[2];
    const float* dist = (const float*)d_in[3];
    const float* We1  = (const float*)d_in[4];
    const float* be1  = (const float*)d_in[5];
    const float* We2  = (const float*)d_in[6];
    const float* be2  = (const float*)d_in[7];
    const float* Wn1  = (const float*)d_in[8];
    const float* bn1  = (const float*)d_in[9];
    const float* Wn2  = (const float*)d_in[10];
    const float* bn2  = (const float*)d_in[11];
    const float* Wc1  = (const float*)d_in[12];
    const float* bc1  = (const float*)d_in[13];
    const float* Wc2  = (const float*)d_in[14];
    float* out = (float*)d_out;

    float* biasC = (float*)((char*)d_ws + WS_BIAS_OFF);
    unsigned short* W1s = (unsigned short*)((char*)d_ws + WS_W1S_OFF);
    unsigned short* W2s = (unsigned short*)((char*)d_ws + WS_W2S_OFF);
    int* counts   = (int*)((char*)d_ws + WS_CNT_OFF);
    int* cursor   = (int*)((char*)d_ws + WS_CUR_OFF);
    int* perm     = (int*)((char*)d_ws + WS_PERM_OFF);
    int* partials = (int*)((char*)d_ws + WS_PART_OFF);
    unsigned short* hbf = (ws_size >= (size_t)WS_HBF_END)
                        ? (unsigned short*)((char*)d_ws + WS_HBF_OFF) : nullptr;

    prep_all_kernel<<<PREP_TOT / 256, 256, 0, stream>>>(
        h, x, We2, be2, Wn1, bn1, Wn2, Wc1, bc1,
        out, biasC, W1s, W2s, counts, hbf);

    hist_kernel<<<N_EDGES / 256, 256, 0, stream>>>(ei, counts);
    scanA_kernel<<<128, 256, 0, stream>>>(counts, partials);
    scanC_kernel<<<128, 256, 0, stream>>>(counts, partials, cursor);
    place_kernel<<<N_EDGES / 256, 256, 0, stream>>>(ei, cursor, perm);

    egnn_mfma_kernel<<<N_EDGES / TE, 512, 0, stream>>>(
        h, x, ei, dist, We1, be1, bn2, Wc2, biasC, W1s, W2s, perm, hbf, out);
}